// Round 6
// baseline (192.608 us; speedup 1.0000x reference)
//
#include <hip/hip_runtime.h>

// B=262144 x C=101 fp32 -> 3 scalars.
//
// R11: R8's proven main loop byte-for-byte (grid-stride, 1024 blocks,
// team-of-16 per row, 7 aligned scalar dword loads j=s+16k, all cross-lane
// via DPP) with ONE structural change: the finalize kernel is fused via the
// last-block-done pattern.
//   * ws layout: [0,16) counter (zeroed by a 16B hipMemsetAsync, the only
//     extra dispatch -- replaces the full finalize dispatch); [16,...)
//     1024 float2 partials.
//   * each block: write partial -> __threadfence() -> thread0
//     atomicAdd(counter); the block seeing old==gridDim-1 runs the
//     IDENTICAL 256-thread finalize body (same strided double accumulation,
//     same shuffle tree, same order -> bit-identical, absmax 0 preserved).
// Post-mortems: R8 (shuffles->DPP) neutral, R9 (4->8 waves/SIMD) slightly
// worse, R10 (full-line global_load_lds staging + counted vmcnt) neutral ->
// main kernel is at its memory floor (~18us for 107MB); remaining
// controllable time is dispatch structure, attacked here.
//
// pen = sum_j max(e_j - e_{j+1}, 0) - e_t with e_j := 0 for j >= 101
// (zero-pad absorbs the +e_100 term; identity validated R4/R5/R8).

#define NC 101
#define LAMBDA_W 1000.0

template <int CTRL>
__device__ __forceinline__ float dpp_mov(float v) {
    // bound_ctrl=true: out-of-row source lanes produce 0
    return __int_as_float(__builtin_amdgcn_update_dpp(
        0, __float_as_int(v), CTRL, 0xf, 0xf, true));
}

// sum of the 16-lane team (DPP row); total lands in lane 15 of each row
__device__ __forceinline__ float team_sum16(float v) {
    v += dpp_mov<0x111>(v);   // row_shr:1
    v += dpp_mov<0x112>(v);   // row_shr:2
    v += dpp_mov<0x114>(v);   // row_shr:4
    v += dpp_mov<0x118>(v);   // row_shr:8
    return v;
}

__global__ __launch_bounds__(256)
void ucl_stream_kernel(const float* __restrict__ x,
                       const int* __restrict__ tgt,
                       unsigned int* __restrict__ counter,  // ws[0,16)
                       float2* __restrict__ partial,        // ws[16,...)
                       float* __restrict__ out,
                       int ngroups, double invB)
{
    const int tid  = threadIdx.x;
    const int lane = tid & 63;
    const int s    = lane & 15;                  // slot within team
    const int gwave  = blockIdx.x * 4 + (tid >> 6);
    const int nwaves = gridDim.x * 4;

    const float fs = (float)s;
    float conc = 0.f, pens = 0.f;

    for (int g = gwave; g < ngroups; g += nwaves) {
        const int row = g * 4 + (lane >> 4);     // team's row
        const float* __restrict__ xr = x + (size_t)row * NC;
        const int t = tgt[row];                  // broadcast within team

        // ---- hoisted predicated loads, j = s + 16k (always 4B-aligned) ----
        float e[7];
#pragma unroll
        for (int k = 0; k < 7; ++k) {
            const int j = s + 16 * k;
            e[k] = (j < NC) ? xr[j] : 0.f;
        }
        // exp; force 0 (not exp(0)=1) on padded lanes
#pragma unroll
        for (int k = 0; k < 7; ++k) {
            const int j = s + 16 * k;
            float ee = __expf(e[k]);
            e[k] = (j < NC) ? ee : 0.f;
        }

        // ---- moments ----
        float S = 0.f, W = 0.f, Q = 0.f;
#pragma unroll
        for (int k = 0; k < 7; ++k) {
            const float fj = fs + (float)(16 * k);
            S += e[k];
            W = fmaf(e[k], fj, W);
            Q = fmaf(e[k], fj * fj, Q);
        }

        // ---- penalty: d_j = e_j - e_{j+1} (e_{101..} = 0), all on VALU ----
        float pen = 0.f;
#pragma unroll
        for (int k = 0; k < 7; ++k) {
            float n1 = dpp_mov<0x101>(e[k]);               // row_shl:1 -> e_{j+1}, 0 at s==15
            float nx = (k < 6) ? dpp_mov<0x11F>(e[k + 1])  // row_shr:15 -> lane15 gets lane0's e[k+1]
                               : 0.f;
            float en = (s == 15) ? nx : n1;
            float d  = e[k] - en;
            pen += fmaxf(d, 0.f);
            const int j = s + 16 * k;
            pen -= (j == t) ? e[k] : 0.f;                  // -e_t by owner
        }

        // ---- team reduce on the VALU pipe (zero DS ops) ----
        S   = team_sum16(S);
        W   = team_sum16(W);
        Q   = team_sum16(Q);
        pen = team_sum16(pen);

        if (s == 15) {                           // row total lives in lane 15
            float pred = W / S;
            float var  = fmaxf(fmaf(-pred, pred, Q / S), 1e-6f);
            float err  = pred - (float)t;
            conc += 0.5f * __logf(var) + err * err / (2.0f * var);
            pens += pen / S;
        }
    }

    // ---- wave reduce (values at lanes 15,31,47,63) ----
    conc += __shfl_down(conc, 16);
    pens += __shfl_down(pens, 16);
    conc += __shfl_down(conc, 32);
    pens += __shfl_down(pens, 32);

    __shared__ float red[8];
    if (lane == 15) {
        red[(tid >> 6) * 2 + 0] = conc;
        red[(tid >> 6) * 2 + 1] = pens;
    }
    __syncthreads();

    __shared__ int is_last;
    if (tid == 0) {
        partial[blockIdx.x] = make_float2(red[0] + red[2] + red[4] + red[6],
                                          red[1] + red[3] + red[5] + red[7]);
        __threadfence();                         // partial visible device-wide
        unsigned int old = atomicAdd(counter, 1u);
        is_last = (old == (unsigned int)gridDim.x - 1u) ? 1 : 0;
    }
    __syncthreads();
    if (!is_last) return;

    // ---- fused finalize: identical body to the old ucl_finalize ----
    __threadfence();                             // acquire all partials
    const int nblocks = gridDim.x;
    double c = 0.0, p = 0.0;
    for (int i = tid; i < nblocks; i += 256) {
        float2 v = partial[i];
        c += (double)v.x;
        p += (double)v.y;
    }
#pragma unroll
    for (int off = 32; off > 0; off >>= 1) {
        c += __shfl_down(c, off);
        p += __shfl_down(p, off);
    }
    __shared__ double sm[8];
    if ((tid & 63) == 0) { sm[(tid >> 6) * 2] = c; sm[(tid >> 6) * 2 + 1] = p; }
    __syncthreads();
    if (tid == 0) {
        double C = (sm[0] + sm[2] + sm[4] + sm[6]) * invB;
        double P = (sm[1] + sm[3] + sm[5] + sm[7]) * invB * LAMBDA_W;
        out[0] = (float)(C + P);
        out[1] = (float)C;
        out[2] = (float)P;
    }
}

extern "C" void kernel_launch(void* const* d_in, const int* in_sizes, int n_in,
                              void* d_out, int out_size, void* d_ws, size_t ws_size,
                              hipStream_t stream)
{
    const float* x   = (const float*)d_in[0];
    const int*   tgt = (const int*)d_in[1];
    float* out = (float*)d_out;

    unsigned int* counter = (unsigned int*)d_ws;           // [0,16)
    float2* partial = (float2*)((char*)d_ws + 16);         // [16,...)

    const int B = in_sizes[1];        // 262144
    const int ngroups = B / 4;        // 65536
    const int blocks = 1024;

    hipMemsetAsync(d_ws, 0, 16, stream);                   // zero the counter
    hipLaunchKernelGGL(ucl_stream_kernel, dim3(blocks), dim3(256), 0, stream,
                       x, tgt, counter, partial, out, ngroups,
                       1.0 / (double)B);
}

// Round 7
// 156.722 us; speedup vs baseline: 1.2290x; 1.2290x over previous
//
#include <hip/hip_runtime.h>

// B=262144 x C=101 fp32 -> 3 scalars.
//
// R12: R8's proven two-kernel structure + compute (grid-stride, 1024 blocks,
// team-of-16 per row, DPP reduce -- 153.9/154.9us baseline), with ONE change:
// the load path. R11 post-mortem (first direct counter sighting): fused
// kernel regressed to 86-91us at VGPR=24 (fusion reverted here), FETCH_SIZE
// = 54.6MB = half the input, and one dispatch ran at ~0 HBM fetch yet still
// 86.6us -> input is largely L3-resident; the kernel is pinned by the read
// path (~3.5 TB/s in R8), NOT by HBM bandwidth. m146 (RMSNorm, 16B/lane
// wave-contiguous VGPR loads) proves 4.89 TB/s read streaming on this chip.
// R8 loads 4B/lane scattered over 4 rows (64B sectors); R7's 16B/lane try
// was invalidated by 404B-row misalignment; R10 used global_load_lds (a
// different HW path, per-lane 16B to LDS). R12 loads each 4-row group
// (1616B = 101 x 16B, so g*1616 is ALWAYS 16B-aligned) as plain float4 to
// VGPRs: lane i takes bytes [16i,16i+16) (1 full + 1 37-lane-predicated
// instr, wave-contiguous full-line requests), stages via a wave-private LDS
// slot (ds_write_b128 + 7 ds_read/lane; DS proven free in R8; writer ==
// reader wave -> no barriers), and feeds the UNCHANGED compute. Next
// group's loads issue at iteration top (register double-buffer,
// compiler-scheduled) so compute x 4 waves covers load latency.
//
// pen = sum_j max(e_j - e_{j+1}, 0) - e_t with e_j := 0 for j >= 101
// (zero-pad absorbs the +e_100 term; identity validated R4/R5/R8).

#define NC 101
#define GRPF 404            // floats per 4-row group (= 101*4)
#define LAMBDA_W 1000.0

typedef float f4 __attribute__((ext_vector_type(4)));

template <int CTRL>
__device__ __forceinline__ float dpp_mov(float v) {
    // bound_ctrl=true: out-of-row source lanes produce 0
    return __int_as_float(__builtin_amdgcn_update_dpp(
        0, __float_as_int(v), CTRL, 0xf, 0xf, true));
}

// sum of the 16-lane team (DPP row); total lands in lane 15 of each row
__device__ __forceinline__ float team_sum16(float v) {
    v += dpp_mov<0x111>(v);   // row_shr:1
    v += dpp_mov<0x112>(v);   // row_shr:2
    v += dpp_mov<0x114>(v);   // row_shr:4
    v += dpp_mov<0x118>(v);   // row_shr:8
    return v;
}

__global__ __launch_bounds__(256)
void ucl_stream_kernel(const float* __restrict__ x,
                       const int* __restrict__ tgt,
                       float2* __restrict__ partial,
                       int ngroups)              // B/4 row-groups
{
    const int tid  = threadIdx.x;
    const int lane = tid & 63;
    const int s    = lane & 15;                  // slot within team
    const int r    = lane >> 4;                  // team = row within group
    const int wid  = tid >> 6;
    const int gwave  = blockIdx.x * 4 + wid;
    const int nwaves = gridDim.x * 4;

    // wave-private staging slot: 404 floats + pad (no double buffer needed:
    // write-after-read ordering within one wave is handled by lgkmcnt)
    __shared__ float slot[4][GRPF + 12];

    const float fs = (float)s;
    float conc = 0.f, pens = 0.f;

    // ---- prologue: load first group's 1616B, 16B/lane, fully aligned ----
    f4 a = {0.f, 0.f, 0.f, 0.f}, b = {0.f, 0.f, 0.f, 0.f};
    if (gwave < ngroups) {
        const f4* gp = (const f4*)(x + (size_t)gwave * GRPF);
        a = gp[lane];                            // bytes [0,1024)
        if (lane < 37) b = gp[64 + lane];        // bytes [1024,1616)
    }

    for (int g = gwave; g < ngroups; g += nwaves) {
        // ---- issue NEXT group's loads first (compiler keeps them in flight
        //      across this iteration's staging + compute) ----
        const int gn = g + nwaves;
        f4 an = {0.f, 0.f, 0.f, 0.f}, bn = {0.f, 0.f, 0.f, 0.f};
        if (gn < ngroups) {
            const f4* gp = (const f4*)(x + (size_t)gn * GRPF);
            an = gp[lane];
            if (lane < 37) bn = gp[64 + lane];
        }

        const int t = tgt[g * 4 + r];            // team's target (4 lanes distinct)

        // ---- stage current group into this wave's slot (no barrier) ----
        f4* sp = (f4*)&slot[wid][0];
        sp[lane] = a;                            // floats [4*lane, 4*lane+4)
        if (lane < 37) sp[64 + lane] = b;        // floats [256+4*lane, ...)

        // ---- gather team layout j = s+16k from the slot ----
        const float* buf = &slot[wid][101 * r];
        float e[7];
#pragma unroll
        for (int k = 0; k < 7; ++k) {
            const int j = s + 16 * k;
            float v  = (j < NC) ? buf[j] : 0.f;
            float ee = __expf(v);
            e[k] = (j < NC) ? ee : 0.f;          // force 0 (not exp(0)=1) on pads
        }

        // ---- moments ----
        float S = 0.f, W = 0.f, Q = 0.f;
#pragma unroll
        for (int k = 0; k < 7; ++k) {
            const float fj = fs + (float)(16 * k);
            S += e[k];
            W = fmaf(e[k], fj, W);
            Q = fmaf(e[k], fj * fj, Q);
        }

        // ---- penalty: d_j = e_j - e_{j+1} (e_{101..} = 0), all on VALU ----
        float pen = 0.f;
#pragma unroll
        for (int k = 0; k < 7; ++k) {
            float n1 = dpp_mov<0x101>(e[k]);               // row_shl:1 -> e_{j+1}, 0 at s==15
            float nx = (k < 6) ? dpp_mov<0x11F>(e[k + 1])  // row_shr:15 -> lane15 gets lane0's e[k+1]
                               : 0.f;
            float en = (s == 15) ? nx : n1;
            float d  = e[k] - en;
            pen += fmaxf(d, 0.f);
            const int j = s + 16 * k;
            pen -= (j == t) ? e[k] : 0.f;                  // -e_t by owner
        }

        // ---- team reduce on the VALU pipe (zero cross-lane DS ops) ----
        S   = team_sum16(S);
        W   = team_sum16(W);
        Q   = team_sum16(Q);
        pen = team_sum16(pen);

        if (s == 15) {                           // row total lives in lane 15
            float pred = W / S;
            float var  = fmaxf(fmaf(-pred, pred, Q / S), 1e-6f);
            float err  = pred - (float)t;
            conc += 0.5f * __logf(var) + err * err / (2.0f * var);
            pens += pen / S;
        }

        a = an; b = bn;                          // rotate register buffer
    }

    // ---- wave reduce (values at lanes 15,31,47,63) ----
    conc += __shfl_down(conc, 16);
    pens += __shfl_down(pens, 16);
    conc += __shfl_down(conc, 32);
    pens += __shfl_down(pens, 32);

    __shared__ float red[8];
    if (lane == 15) {
        red[wid * 2 + 0] = conc;
        red[wid * 2 + 1] = pens;
    }
    __syncthreads();
    if (tid == 0)
        partial[blockIdx.x] = make_float2(red[0] + red[2] + red[4] + red[6],
                                          red[1] + red[3] + red[5] + red[7]);
}

__global__ __launch_bounds__(256)
void ucl_finalize(const float2* __restrict__ partial,
                  float* __restrict__ out,
                  int nblocks, double invB)
{
    const int tid = threadIdx.x;
    double c = 0.0, p = 0.0;
    for (int i = tid; i < nblocks; i += 256) {
        float2 v = partial[i];
        c += (double)v.x;
        p += (double)v.y;
    }
#pragma unroll
    for (int off = 32; off > 0; off >>= 1) {
        c += __shfl_down(c, off);
        p += __shfl_down(p, off);
    }
    __shared__ double sm[8];
    if ((tid & 63) == 0) { sm[(tid >> 6) * 2] = c; sm[(tid >> 6) * 2 + 1] = p; }
    __syncthreads();
    if (tid == 0) {
        double C = (sm[0] + sm[2] + sm[4] + sm[6]) * invB;
        double P = (sm[1] + sm[3] + sm[5] + sm[7]) * invB * LAMBDA_W;
        out[0] = (float)(C + P);
        out[1] = (float)C;
        out[2] = (float)P;
    }
}

extern "C" void kernel_launch(void* const* d_in, const int* in_sizes, int n_in,
                              void* d_out, int out_size, void* d_ws, size_t ws_size,
                              hipStream_t stream)
{
    const float* x   = (const float*)d_in[0];
    const int*   tgt = (const int*)d_in[1];
    float* out = (float*)d_out;
    float2* partial = (float2*)d_ws;

    const int B = in_sizes[1];        // 262144
    const int ngroups = B / 4;        // 65536
    const int blocks = 1024;

    hipLaunchKernelGGL(ucl_stream_kernel, dim3(blocks), dim3(256), 0, stream,
                       x, tgt, partial, ngroups);
    hipLaunchKernelGGL(ucl_finalize, dim3(1), dim3(256), 0, stream,
                       partial, out, blocks, 1.0 / (double)B);
}